// Round 22
// baseline (84.932 us; speedup 1.0000x reference)
//
#include <hip/hip_runtime.h>

#define L_LEN 131072
#define H_DIM 128
#define P_DIM 128
#define SEG 32
#define NSEG (L_LEN / SEG)       // 4096
#define ROWS 64
#define NBLK (L_LEN / ROWS)      // 2048

typedef unsigned int uint32;
typedef unsigned short u16;
typedef short bf16x8 __attribute__((ext_vector_type(8)));
typedef float f32x4 __attribute__((ext_vector_type(4)));

// ---- workspace layout (float offsets) ----
constexpr size_t OFF_DA  = 0;                          // dA [128] cplx
constexpr size_t OFF_E   = OFF_DA + 256;               // E [NSEG][128] cplx
constexpr size_t OFF_HIN = OFF_E + (size_t)NSEG * 256; // Hin [NSEG][128] cplx
constexpr size_t OFF_W1F = OFF_HIN + (size_t)NSEG * 256;  // 65536 u16 = 32768 fl
constexpr size_t OFF_W2F = OFF_W1F + 32768;               // 65536 u16

__device__ __forceinline__ u16 f2bf(float v) {
    uint32 u = __builtin_bit_cast(uint32, v);
    uint32 r = u + 0x7FFFu + ((u >> 16) & 1u);
    return (u16)(r >> 16);
}
__device__ __forceinline__ float bf2f(u16 h) {
    uint32 u = ((uint32)h) << 16;
    return __builtin_bit_cast(float, u);
}
// HW packed f32->bf16 (RNE), 1 VALU op for 2 values
__device__ __forceinline__ uint32 cvtpk(float lo, float hi) {
    uint32 r;
    asm("v_cvt_pk_bf16_f32 %0, %1, %2" : "=v"(r) : "v"(lo), "v"(hi));
    return r;
}
__device__ __forceinline__ float2 cfma(float2 a, float2 h, float2 c) {
    float2 r;
    r.x = fmaf(a.x, h.x, fmaf(-a.y, h.y, c.x));
    r.y = fmaf(a.x, h.y, fmaf(a.y, h.x, c.y));
    return r;
}
__device__ __forceinline__ float2 cmul(float2 a, float2 b) {
    return make_float2(fmaf(a.x, b.x, -a.y * b.y), fmaf(a.x, b.y, a.y * b.x));
}
__device__ __forceinline__ float2 unpk(uint32 w) {
    return make_float2(bf2f((u16)(w & 0xffffu)), bf2f((u16)(w >> 16)));
}

// ---- k0: weight tables (sc inline) + block 0 does dA ----
__global__ void k0(const float* __restrict__ Arl, const float* __restrict__ Ai,
                   const float* __restrict__ invdt,
                   const float* __restrict__ Bre, const float* __restrict__ Bim,
                   const float* __restrict__ Cre, const float* __restrict__ Cim,
                   float* __restrict__ dA,
                   u16* __restrict__ W1F, u16* __restrict__ W2F) {
    int tid = blockIdx.x * 256 + threadIdx.x;    // 0..8191
    int lane = tid & 63;
    int fb = (tid >> 6) & 63;
    int ar = lane & 15, aq = lane >> 4;
    ushort4 hiA, hiB, loA, loB;
    u16* dst;
    if (tid < 4096) {
        int kt = fb >> 4, cf = fb & 15;
        int q = cf * 16 + ar;
        int p = q >> 1, c = q & 1;
        int h0 = kt * 32 + aq * 8;
        float idt = invdt[p];
        float dt = (idt > 20.f) ? idt : log1pf(expf(idt));
        float arl = Arl[p], aii = Ai[p];
        float zr = 0.5f * dt * arl, zi = 0.5f * dt * aii;
        float drr = 1.f - zr, dii = -zi;
        float inv = 1.f / (drr * drr + dii * dii);
        float blr = drr * inv, bli = -dii * inv;
        float2 s = make_float2(blr * dt, bli * dt);
        u16 hh[8], ll[8];
        #pragma unroll
        for (int j = 0; j < 8; ++j) {
            float br = Bre[p * H_DIM + h0 + j], bi = Bim[p * H_DIM + h0 + j];
            float re = fmaf(s.x, br, -s.y * bi);
            float im = fmaf(s.x, bi,  s.y * br);
            float v = c ? im : re;
            u16 h = f2bf(v); hh[j] = h; ll[j] = f2bf(v - bf2f(h));
        }
        hiA = make_ushort4(hh[0], hh[1], hh[2], hh[3]);
        hiB = make_ushort4(hh[4], hh[5], hh[6], hh[7]);
        loA = make_ushort4(ll[0], ll[1], ll[2], ll[3]);
        loB = make_ushort4(ll[4], ll[5], ll[6], ll[7]);
        dst = W1F + fb * 1024 + lane * 8;
    } else {
        int kk = fb >> 3, cf = fb & 7;
        int h = cf * 16 + ar;
        int q0 = kk * 32 + aq * 8;
        u16 hh[8], ll[8];
        #pragma unroll
        for (int j = 0; j < 8; ++j) {
            int q = q0 + j; int p = q >> 1;
            float v = (q & 1) ? (-2.f * Cim[h * P_DIM + p]) : (2.f * Cre[h * P_DIM + p]);
            u16 hv = f2bf(v); hh[j] = hv; ll[j] = f2bf(v - bf2f(hv));
        }
        hiA = make_ushort4(hh[0], hh[1], hh[2], hh[3]);
        hiB = make_ushort4(hh[4], hh[5], hh[6], hh[7]);
        loA = make_ushort4(ll[0], ll[1], ll[2], ll[3]);
        loB = make_ushort4(ll[4], ll[5], ll[6], ll[7]);
        dst = W2F + fb * 1024 + lane * 8;
    }
    *(ushort4*)(dst)       = hiA;
    *(ushort4*)(dst + 4)   = hiB;
    *(ushort4*)(dst + 512) = loA;
    *(ushort4*)(dst + 516) = loB;

    if (blockIdx.x == 0 && threadIdx.x < 128) {
        int p = threadIdx.x;
        float idt = invdt[p];
        float dt = (idt > 20.f) ? idt : log1pf(expf(idt));
        float arl = Arl[p], aii = Ai[p];
        float zr = 0.5f * dt * arl, zi = 0.5f * dt * aii;
        float drr = 1.f - zr, dii = -zi;
        float inv = 1.f / (drr * drr + dii * dii);
        float blr = drr * inv, bli = -dii * inv;
        float nr = 1.f + zr, ni = zi;
        dA[2 * p]     = fmaf(blr, nr, -bli * ni);
        dA[2 * p + 1] = fmaf(blr, ni,  bli * nr);
    }
}

// ---- k1: E-producer, no LDS transpose. stage x -> GEMM1 -> in-register
//      weighted reduce (E = sum dA^{31-i} Bu_i) via shuffles -> E store ----
__global__ __launch_bounds__(256) void k1(const float* __restrict__ x,
                                          const u16* __restrict__ W1F,
                                          const float* __restrict__ dA,
                                          float* __restrict__ E) {
    __shared__ __align__(16) u16 As_hi[64 * 136];   // 17.4 KB
    int t = threadIdx.x, lane = t & 63, wid = t >> 6;
    size_t l0 = (size_t)blockIdx.x * ROWS;
    int ar = lane & 15, aq = lane >> 4, ak = aq * 8;

    bf16x8 bhp[4][4];
    #pragma unroll
    for (int kt = 0; kt < 4; ++kt)
        #pragma unroll
        for (int nf = 0; nf < 4; ++nf)
            bhp[kt][nf] = *(const bf16x8*)(W1F + (size_t)(kt * 16 + wid * 4 + nf) * 1024 + lane * 8);

    float4 xv[8];
    #pragma unroll
    for (int j = 0; j < 8; ++j) {
        int f = j * 256 + t; int row = f >> 5, c4 = f & 31;
        xv[j] = *(const float4*)(x + (l0 + row) * H_DIM + c4 * 4);
    }
    #pragma unroll
    for (int j = 0; j < 8; ++j) {
        int f = j * 256 + t; int row = f >> 5, c4 = f & 31;
        uint2 wv;
        wv.x = cvtpk(xv[j].x, xv[j].y);
        wv.y = cvtpk(xv[j].z, xv[j].w);
        *(uint2*)&As_hi[row * 136 + c4 * 4] = wv;
    }
    __syncthreads();

    f32x4 acc[4][4];
    #pragma unroll
    for (int a = 0; a < 4; ++a)
        #pragma unroll
        for (int b = 0; b < 4; ++b) acc[a][b] = (f32x4)0.f;
    #pragma unroll
    for (int kt = 0; kt < 4; ++kt) {
        bf16x8 ah[4];
        #pragma unroll
        for (int mf = 0; mf < 4; ++mf)
            ah[mf] = *(const bf16x8*)&As_hi[(mf * 16 + ar) * 136 + kt * 32 + ak];
        #pragma unroll
        for (int nf = 0; nf < 4; ++nf)
            #pragma unroll
            for (int mf = 0; mf < 4; ++mf)
                acc[mf][nf] = __builtin_amdgcn_mfma_f32_16x16x32_bf16(ah[mf], bhp[kt][nf], acc[mf][nf], 0, 0, 0);
    }

    // ---- in-register E: lanes pair re/im via shfl_xor(1); weights from
    //      repeated squaring; 4-lane (q) reduce via shfl_xor(16/32) ----
    // acc element (mf,nf,r): row = mf*16 + aq*4 + r, col = wid*64 + nf*16 + ar.
    // seg s = row>>5 (mf<2 -> s0, mf>=2 -> s1); in-seg row i = (mf&1)*16+4q+r;
    // weight = dA[p]^{31-i} = P16^{1-(mf&1)} * D4^{3-q} * dA^{3-r}.
    float sgn = (ar & 1) ? 1.f : -1.f;
    #pragma unroll
    for (int nf = 0; nf < 4; ++nf) {
        int p = wid * 32 + nf * 8 + (ar >> 1);
        float2 a = ((const float2*)dA)[p];
        float2 d2 = cmul(a, a), d3 = cmul(d2, a);
        float2 D4 = cmul(d2, d2), D8 = cmul(D4, D4), P16 = cmul(D8, D8);
        float2 D12 = cmul(D8, D4);
        float2 Q = (aq == 0) ? D12 : (aq == 1) ? D8 : (aq == 2) ? D4 : make_float2(1.f, 0.f);
        float2 QR[4];
        QR[0] = cmul(Q, d3); QR[1] = cmul(Q, d2); QR[2] = cmul(Q, a); QR[3] = Q;
        float2 WA[4];
        #pragma unroll
        for (int r = 0; r < 4; ++r) WA[r] = cmul(P16, QR[r]);
        float e0 = 0.f, e1 = 0.f;
        #pragma unroll
        for (int mf = 0; mf < 4; ++mf)
            #pragma unroll
            for (int r = 0; r < 4; ++r) {
                float own = acc[mf][nf][r];
                float oth = __shfl_xor(own, 1, 64);
                float2 w = (mf & 1) ? QR[r] : WA[r];
                float tv = fmaf(w.x, own, sgn * w.y * oth);
                if (mf < 2) e0 += tv; else e1 += tv;
            }
        e0 += __shfl_xor(e0, 16, 64); e0 += __shfl_xor(e0, 32, 64);
        e1 += __shfl_xor(e1, 16, 64); e1 += __shfl_xor(e1, 32, 64);
        if (aq == 0) {
            E[(((size_t)blockIdx.x * 2 + 0) * P_DIM + p) * 2 + (ar & 1)] = e0;
            E[(((size_t)blockIdx.x * 2 + 1) * P_DIM + p) * 2 + (ar & 1)] = e1;
        }
    }
}

// ---- k3: per-mode scan over 4096 seg states, wave-shuffle version ----
__global__ __launch_bounds__(256) void k3(const float* __restrict__ E,
                                          const float* __restrict__ dA,
                                          float* __restrict__ Hin) {
    __shared__ float4 wagg[4];
    int m = blockIdx.x, t = threadIdx.x;
    int lane = t & 63, w = t >> 6;
    float2 aS = ((const float2*)dA)[m];
    #pragma unroll
    for (int i = 0; i < 5; ++i) aS = cmul(aS, aS);     // dA^32
    const float2* e = (const float2*)E;
    float2 ebuf[16];
    #pragma unroll
    for (int i = 0; i < 16; ++i) ebuf[i] = e[(size_t)(t * 16 + i) * P_DIM + m];
    float2 Bv = ebuf[0];
    #pragma unroll
    for (int i = 1; i < 16; ++i) Bv = cfma(aS, Bv, ebuf[i]);
    float2 Av = aS;
    #pragma unroll
    for (int i = 0; i < 4; ++i) Av = cmul(Av, Av);     // aS^16

    #pragma unroll
    for (int d = 1; d < 64; d <<= 1) {
        float uAx = __shfl_up(Av.x, (unsigned)d, 64);
        float uAy = __shfl_up(Av.y, (unsigned)d, 64);
        float uBx = __shfl_up(Bv.x, (unsigned)d, 64);
        float uBy = __shfl_up(Bv.y, (unsigned)d, 64);
        if (lane >= d) {
            float2 uA = make_float2(uAx, uAy), uB = make_float2(uBx, uBy);
            Bv = cfma(Av, uB, Bv);
            Av = cmul(uA, Av);
        }
    }
    if (lane == 63) wagg[w] = make_float4(Av.x, Av.y, Bv.x, Bv.y);
    __syncthreads();
    float2 Pb = make_float2(0.f, 0.f);
    for (int i = 0; i < w; ++i) {
        float4 u = wagg[i];
        float2 Wa = make_float2(u.x, u.y), Wb = make_float2(u.z, u.w);
        Pb = cfma(Wa, Pb, Wb);
    }
    float eAx = __shfl_up(Av.x, 1u, 64), eAy = __shfl_up(Av.y, 1u, 64);
    float eBx = __shfl_up(Bv.x, 1u, 64), eBy = __shfl_up(Bv.y, 1u, 64);
    float2 eA = make_float2(eAx, eAy), eB = make_float2(eBx, eBy);
    if (lane == 0) { eA = make_float2(1.f, 0.f); eB = make_float2(0.f, 0.f); }
    float2 pre = cfma(eA, Pb, eB);
    float2* hin = (float2*)Hin;
    #pragma unroll
    for (int i = 0; i < 16; ++i) {
        hin[(size_t)(t * 16 + i) * P_DIM + m] = pre;
        pre = cfma(aS, pre, ebuf[i]);
    }
}

// ---- k4: full recompute pass; x kept in registers through to the epilogue ----
__global__ __launch_bounds__(256) void k4(const float* __restrict__ x,
                                          const u16* __restrict__ W1F,
                                          const u16* __restrict__ W2F,
                                          const float* __restrict__ dA,
                                          const float* __restrict__ Hin,
                                          const float* __restrict__ Dv,
                                          float* __restrict__ y) {
    __shared__ __align__(16) char smem[33280];
    u16*   As_hi = (u16*)smem;               // [64][136] during stage
    u16*   SB    = (u16*)smem;               // [64][256] swizzled bf16, aliases As
    float* SBF   = (float*)smem;             // [64][130] f32 y-tile (after GEMM2)
    int t = threadIdx.x, lane = t & 63, wid = t >> 6;
    size_t l0 = (size_t)blockIdx.x * ROWS;
    int ar = lane & 15, aq = lane >> 4, ak = aq * 8;

    // W1F prefetch
    bf16x8 bhp[4][4];
    #pragma unroll
    for (int kt = 0; kt < 4; ++kt)
        #pragma unroll
        for (int nf = 0; nf < 4; ++nf)
            bhp[kt][nf] = *(const bf16x8*)(W1F + (size_t)(kt * 16 + wid * 4 + nf) * 1024 + lane * 8);

    // stage x -> bf16 LDS; KEEP xv in registers for the epilogue
    float4 xv[8];
    #pragma unroll
    for (int j = 0; j < 8; ++j) {
        int f = j * 256 + t; int row = f >> 5, c4 = f & 31;
        xv[j] = *(const float4*)(x + (l0 + row) * H_DIM + c4 * 4);
    }
    #pragma unroll
    for (int j = 0; j < 8; ++j) {
        int f = j * 256 + t; int row = f >> 5, c4 = f & 31;
        uint2 wv;
        wv.x = cvtpk(xv[j].x, xv[j].y);
        wv.y = cvtpk(xv[j].z, xv[j].w);
        *(uint2*)&As_hi[row * 136 + c4 * 4] = wv;
    }
    __syncthreads();

    // GEMM1: Bu = X @ W1
    {
        f32x4 acc[4][4];
        #pragma unroll
        for (int a = 0; a < 4; ++a)
            #pragma unroll
            for (int b = 0; b < 4; ++b) acc[a][b] = (f32x4)0.f;
        #pragma unroll
        for (int kt = 0; kt < 4; ++kt) {
            bf16x8 ah[4];
            #pragma unroll
            for (int mf = 0; mf < 4; ++mf)
                ah[mf] = *(const bf16x8*)&As_hi[(mf * 16 + ar) * 136 + kt * 32 + ak];
            #pragma unroll
            for (int nf = 0; nf < 4; ++nf)
                #pragma unroll
                for (int mf = 0; mf < 4; ++mf)
                    acc[mf][nf] = __builtin_amdgcn_mfma_f32_16x16x32_bf16(ah[mf], bhp[kt][nf], acc[mf][nf], 0, 0, 0);
        }
        __syncthreads();   // As reads done before SB overwrite
        int sr = aq * 4;
        #pragma unroll
        for (int mf = 0; mf < 4; ++mf)
            #pragma unroll
            for (int nf = 0; nf < 4; ++nf) {
                int col = wid * 64 + nf * 16 + ar;
                uint32 w01 = cvtpk(acc[mf][nf][0], acc[mf][nf][1]);
                uint32 w23 = cvtpk(acc[mf][nf][2], acc[mf][nf][3]);
                int r0 = mf * 16 + sr;
                SB[(r0 + 0) * 256 + (((col >> 3) ^ ((r0 + 0) & 7)) << 3) + (col & 7)] = (u16)w01;
                SB[(r0 + 1) * 256 + (((col >> 3) ^ ((r0 + 1) & 7)) << 3) + (col & 7)] = (u16)(w01 >> 16);
                SB[(r0 + 2) * 256 + (((col >> 3) ^ ((r0 + 2) & 7)) << 3) + (col & 7)] = (u16)w23;
                SB[(r0 + 3) * 256 + (((col >> 3) ^ ((r0 + 3) & 7)) << 3) + (col & 7)] = (u16)(w23 >> 16);
            }
    }
    __syncthreads();

    // W2F prefetch (GEMM1 acc dead; loads overlap the scan below)
    bf16x8 bh2[8][2];
    #pragma unroll
    for (int kk = 0; kk < 8; ++kk)
        #pragma unroll
        for (int nf = 0; nf < 2; ++nf)
            bh2[kk][nf] = *(const bf16x8*)(W2F + (size_t)(kk * 8 + wid * 2 + nf) * 1024 + lane * 8);

    // Hin-seeded scan: 2 segs x 128 modes
    {
        int s = t >> 7, p = t & 127;
        float2 a = ((const float2*)dA)[p];
        float2 h = ((const float2*)Hin)[((size_t)blockIdx.x * 2 + s) * P_DIM + p];
        uint32 buf[SEG];
        #pragma unroll
        for (int i = 0; i < SEG; ++i) {
            int row = s * 32 + i;
            buf[i] = *(const uint32*)&SB[row * 256 + (((p >> 2) ^ (row & 7)) << 3) + (p & 3) * 2];
        }
        #pragma unroll
        for (int i = 0; i < SEG; ++i) {
            h = cfma(a, h, unpk(buf[i]));
            buf[i] = cvtpk(h.x, h.y);
        }
        #pragma unroll
        for (int i = 0; i < SEG; ++i) {
            int row = s * 32 + i;
            *(uint32*)&SB[row * 256 + (((p >> 2) ^ (row & 7)) << 3) + (p & 3) * 2] = buf[i];
        }
    }
    __syncthreads();

    // GEMM2: y = h @ W2^T (64x32 wave tiles)
    f32x4 acc2[4][2];
    #pragma unroll
    for (int a = 0; a < 4; ++a)
        #pragma unroll
        for (int b = 0; b < 2; ++b) acc2[a][b] = (f32x4)0.f;
    #pragma unroll
    for (int kk = 0; kk < 8; ++kk) {
        bf16x8 af[4];
        #pragma unroll
        for (int mf = 0; mf < 4; ++mf) {
            int row = mf * 16 + ar;
            int blk = kk * 4 + aq;
            af[mf] = *(const bf16x8*)&SB[row * 256 + ((blk ^ (row & 7)) << 3)];
        }
        #pragma unroll
        for (int nf = 0; nf < 2; ++nf)
            #pragma unroll
            for (int mf = 0; mf < 4; ++mf)
                acc2[mf][nf] = __builtin_amdgcn_mfma_f32_16x16x32_bf16(af[mf], bh2[kk][nf], acc2[mf][nf], 0, 0, 0);
    }
    __syncthreads();   // SB reads done before SBF overwrite

    // acc2 -> SBF[64][130]
    int sr = aq * 4;
    #pragma unroll
    for (int mf = 0; mf < 4; ++mf)
        #pragma unroll
        for (int nf = 0; nf < 2; ++nf)
            #pragma unroll
            for (int r = 0; r < 4; ++r) {
                int row = mf * 16 + sr + r;
                int col = wid * 32 + nf * 16 + ar;
                SBF[row * 130 + col] = acc2[mf][nf][r];
            }
    __syncthreads();

    // y write: coalesced float4 rows; x comes from retained registers
    int c4 = t & 31;
    float4 dv = *(const float4*)(Dv + c4 * 4);
    #pragma unroll
    for (int j = 0; j < 8; ++j) {
        int row = j * 8 + (t >> 5);
        float4 sv = *(float4*)&SBF[row * 130 + c4 * 4];
        float4 out;
        out.x = fmaf(xv[j].x, dv.x, sv.x);
        out.y = fmaf(xv[j].y, dv.y, sv.y);
        out.z = fmaf(xv[j].z, dv.z, sv.z);
        out.w = fmaf(xv[j].w, dv.w, sv.w);
        *(float4*)(y + (l0 + row) * H_DIM + c4 * 4) = out;
    }
}

extern "C" void kernel_launch(void* const* d_in, const int* in_sizes, int n_in,
                              void* d_out, int out_size, void* d_ws, size_t ws_size,
                              hipStream_t stream) {
    const float* x     = (const float*)d_in[0];
    const float* Arl   = (const float*)d_in[1];
    const float* Ai    = (const float*)d_in[2];
    const float* Bre   = (const float*)d_in[3];
    const float* Bim   = (const float*)d_in[4];
    const float* Cre   = (const float*)d_in[5];
    const float* Cim   = (const float*)d_in[6];
    const float* Dv    = (const float*)d_in[7];
    const float* invdt = (const float*)d_in[8];
    float* y  = (float*)d_out;
    float* ws = (float*)d_ws;

    u16* w1f = (u16*)(ws + OFF_W1F);
    u16* w2f = (u16*)(ws + OFF_W2F);

    k0<<<32, 256, 0, stream>>>(Arl, Ai, invdt, Bre, Bim, Cre, Cim,
                               ws + OFF_DA, w1f, w2f);
    k1<<<NBLK, 256, 0, stream>>>(x, w1f, ws + OFF_DA, ws + OFF_E);
    k3<<<128, 256, 0, stream>>>(ws + OFF_E, ws + OFF_DA, ws + OFF_HIN);
    k4<<<NBLK, 256, 0, stream>>>(x, w1f, w2f, ws + OFF_DA,
                                 ws + OFF_HIN, Dv, y);
}

// Round 23
// 81.576 us; speedup vs baseline: 1.0411x; 1.0411x over previous
//
#include <hip/hip_runtime.h>

#define L_LEN 131072
#define H_DIM 128
#define P_DIM 128
#define SEG 32
#define NSEG (L_LEN / SEG)       // 4096
#define ROWS 64
#define NBLK (L_LEN / ROWS)      // 2048

typedef unsigned int uint32;
typedef unsigned short u16;
typedef short bf16x8 __attribute__((ext_vector_type(8)));
typedef float f32x4 __attribute__((ext_vector_type(4)));

// ---- workspace layout (float offsets) ----
constexpr size_t OFF_DA  = 0;                          // dA [128] cplx
constexpr size_t OFF_E   = OFF_DA + 256;               // E [NSEG][128] cplx
constexpr size_t OFF_HIN = OFF_E + (size_t)NSEG * 256; // Hin [NSEG][128] cplx
constexpr size_t OFF_W1F = OFF_HIN + (size_t)NSEG * 256;  // 65536 u16 = 32768 fl
constexpr size_t OFF_W2F = OFF_W1F + 32768;               // 65536 u16

__device__ __forceinline__ u16 f2bf(float v) {
    uint32 u = __builtin_bit_cast(uint32, v);
    uint32 r = u + 0x7FFFu + ((u >> 16) & 1u);
    return (u16)(r >> 16);
}
__device__ __forceinline__ float bf2f(u16 h) {
    uint32 u = ((uint32)h) << 16;
    return __builtin_bit_cast(float, u);
}
// HW packed f32->bf16 (RNE), 1 VALU op for 2 values
__device__ __forceinline__ uint32 cvtpk(float lo, float hi) {
    uint32 r;
    asm("v_cvt_pk_bf16_f32 %0, %1, %2" : "=v"(r) : "v"(lo), "v"(hi));
    return r;
}
__device__ __forceinline__ float2 cfma(float2 a, float2 h, float2 c) {
    float2 r;
    r.x = fmaf(a.x, h.x, fmaf(-a.y, h.y, c.x));
    r.y = fmaf(a.x, h.y, fmaf(a.y, h.x, c.y));
    return r;
}
__device__ __forceinline__ float2 cmul(float2 a, float2 b) {
    return make_float2(fmaf(a.x, b.x, -a.y * b.y), fmaf(a.x, b.y, a.y * b.x));
}
__device__ __forceinline__ float2 unpk(uint32 w) {
    return make_float2(bf2f((u16)(w & 0xffffu)), bf2f((u16)(w >> 16)));
}

// ---- k0: weight tables (sc inline) + block 0 does dA ----
__global__ void k0(const float* __restrict__ Arl, const float* __restrict__ Ai,
                   const float* __restrict__ invdt,
                   const float* __restrict__ Bre, const float* __restrict__ Bim,
                   const float* __restrict__ Cre, const float* __restrict__ Cim,
                   float* __restrict__ dA,
                   u16* __restrict__ W1F, u16* __restrict__ W2F) {
    int tid = blockIdx.x * 256 + threadIdx.x;    // 0..8191
    int lane = tid & 63;
    int fb = (tid >> 6) & 63;
    int ar = lane & 15, aq = lane >> 4;
    ushort4 hiA, hiB, loA, loB;
    u16* dst;
    if (tid < 4096) {
        int kt = fb >> 4, cf = fb & 15;
        int q = cf * 16 + ar;
        int p = q >> 1, c = q & 1;
        int h0 = kt * 32 + aq * 8;
        float idt = invdt[p];
        float dt = (idt > 20.f) ? idt : log1pf(expf(idt));
        float arl = Arl[p], aii = Ai[p];
        float zr = 0.5f * dt * arl, zi = 0.5f * dt * aii;
        float drr = 1.f - zr, dii = -zi;
        float inv = 1.f / (drr * drr + dii * dii);
        float blr = drr * inv, bli = -dii * inv;
        float2 s = make_float2(blr * dt, bli * dt);
        u16 hh[8], ll[8];
        #pragma unroll
        for (int j = 0; j < 8; ++j) {
            float br = Bre[p * H_DIM + h0 + j], bi = Bim[p * H_DIM + h0 + j];
            float re = fmaf(s.x, br, -s.y * bi);
            float im = fmaf(s.x, bi,  s.y * br);
            float v = c ? im : re;
            u16 h = f2bf(v); hh[j] = h; ll[j] = f2bf(v - bf2f(h));
        }
        hiA = make_ushort4(hh[0], hh[1], hh[2], hh[3]);
        hiB = make_ushort4(hh[4], hh[5], hh[6], hh[7]);
        loA = make_ushort4(ll[0], ll[1], ll[2], ll[3]);
        loB = make_ushort4(ll[4], ll[5], ll[6], ll[7]);
        dst = W1F + fb * 1024 + lane * 8;
    } else {
        int kk = fb >> 3, cf = fb & 7;
        int h = cf * 16 + ar;
        int q0 = kk * 32 + aq * 8;
        u16 hh[8], ll[8];
        #pragma unroll
        for (int j = 0; j < 8; ++j) {
            int q = q0 + j; int p = q >> 1;
            float v = (q & 1) ? (-2.f * Cim[h * P_DIM + p]) : (2.f * Cre[h * P_DIM + p]);
            u16 hv = f2bf(v); hh[j] = hv; ll[j] = f2bf(v - bf2f(hv));
        }
        hiA = make_ushort4(hh[0], hh[1], hh[2], hh[3]);
        hiB = make_ushort4(hh[4], hh[5], hh[6], hh[7]);
        loA = make_ushort4(ll[0], ll[1], ll[2], ll[3]);
        loB = make_ushort4(ll[4], ll[5], ll[6], ll[7]);
        dst = W2F + fb * 1024 + lane * 8;
    }
    *(ushort4*)(dst)       = hiA;
    *(ushort4*)(dst + 4)   = hiB;
    *(ushort4*)(dst + 512) = loA;
    *(ushort4*)(dst + 516) = loB;

    if (blockIdx.x == 0 && threadIdx.x < 128) {
        int p = threadIdx.x;
        float idt = invdt[p];
        float dt = (idt > 20.f) ? idt : log1pf(expf(idt));
        float arl = Arl[p], aii = Ai[p];
        float zr = 0.5f * dt * arl, zi = 0.5f * dt * aii;
        float drr = 1.f - zr, dii = -zi;
        float inv = 1.f / (drr * drr + dii * dii);
        float blr = drr * inv, bli = -dii * inv;
        float nr = 1.f + zr, ni = zi;
        dA[2 * p]     = fmaf(blr, nr, -bli * ni);
        dA[2 * p + 1] = fmaf(blr, ni,  bli * nr);
    }
}

// ---- k1: E-producer. stage x -> GEMM1 -> SB -> zero-seeded Horner -> E ----
__global__ __launch_bounds__(256) void k1(const float* __restrict__ x,
                                          const u16* __restrict__ W1F,
                                          const float* __restrict__ dA,
                                          float* __restrict__ E) {
    __shared__ __align__(16) char smem[32768];
    u16* As_hi = (u16*)smem;                 // [64][136]
    u16* SB    = (u16*)smem;                 // [64][256], aliases As
    int t = threadIdx.x, lane = t & 63, wid = t >> 6;
    size_t l0 = (size_t)blockIdx.x * ROWS;
    int ar = lane & 15, aq = lane >> 4, ak = aq * 8;

    bf16x8 bhp[4][4];
    #pragma unroll
    for (int kt = 0; kt < 4; ++kt)
        #pragma unroll
        for (int nf = 0; nf < 4; ++nf)
            bhp[kt][nf] = *(const bf16x8*)(W1F + (size_t)(kt * 16 + wid * 4 + nf) * 1024 + lane * 8);

    float4 xv[8];
    #pragma unroll
    for (int j = 0; j < 8; ++j) {
        int f = j * 256 + t; int row = f >> 5, c4 = f & 31;
        xv[j] = *(const float4*)(x + (l0 + row) * H_DIM + c4 * 4);
    }
    #pragma unroll
    for (int j = 0; j < 8; ++j) {
        int f = j * 256 + t; int row = f >> 5, c4 = f & 31;
        uint2 wv;
        wv.x = cvtpk(xv[j].x, xv[j].y);
        wv.y = cvtpk(xv[j].z, xv[j].w);
        *(uint2*)&As_hi[row * 136 + c4 * 4] = wv;
    }
    __syncthreads();

    f32x4 acc[4][4];
    #pragma unroll
    for (int a = 0; a < 4; ++a)
        #pragma unroll
        for (int b = 0; b < 4; ++b) acc[a][b] = (f32x4)0.f;
    #pragma unroll
    for (int kt = 0; kt < 4; ++kt) {
        bf16x8 ah[4];
        #pragma unroll
        for (int mf = 0; mf < 4; ++mf)
            ah[mf] = *(const bf16x8*)&As_hi[(mf * 16 + ar) * 136 + kt * 32 + ak];
        #pragma unroll
        for (int nf = 0; nf < 4; ++nf)
            #pragma unroll
            for (int mf = 0; mf < 4; ++mf)
                acc[mf][nf] = __builtin_amdgcn_mfma_f32_16x16x32_bf16(ah[mf], bhp[kt][nf], acc[mf][nf], 0, 0, 0);
    }
    __syncthreads();   // As reads done before SB overwrite

    int sr = aq * 4;
    #pragma unroll
    for (int mf = 0; mf < 4; ++mf)
        #pragma unroll
        for (int nf = 0; nf < 4; ++nf) {
            int col = wid * 64 + nf * 16 + ar;
            uint32 w01 = cvtpk(acc[mf][nf][0], acc[mf][nf][1]);
            uint32 w23 = cvtpk(acc[mf][nf][2], acc[mf][nf][3]);
            int r0 = mf * 16 + sr;
            SB[(r0 + 0) * 256 + (((col >> 3) ^ ((r0 + 0) & 7)) << 3) + (col & 7)] = (u16)w01;
            SB[(r0 + 1) * 256 + (((col >> 3) ^ ((r0 + 1) & 7)) << 3) + (col & 7)] = (u16)(w01 >> 16);
            SB[(r0 + 2) * 256 + (((col >> 3) ^ ((r0 + 2) & 7)) << 3) + (col & 7)] = (u16)w23;
            SB[(r0 + 3) * 256 + (((col >> 3) ^ ((r0 + 3) & 7)) << 3) + (col & 7)] = (u16)(w23 >> 16);
        }
    __syncthreads();

    // zero-seeded Horner over each seg -> E (no write-back, no HL)
    {
        int s = t >> 7, p = t & 127;
        float2 a = ((const float2*)dA)[p];
        uint32 buf[SEG];
        #pragma unroll
        for (int i = 0; i < SEG; ++i) {
            int row = s * 32 + i;
            buf[i] = *(const uint32*)&SB[row * 256 + (((p >> 2) ^ (row & 7)) << 3) + (p & 3) * 2];
        }
        float2 e = make_float2(0.f, 0.f);
        #pragma unroll
        for (int i = 0; i < SEG; ++i) e = cfma(a, e, unpk(buf[i]));
        ((float2*)E)[((size_t)blockIdx.x * 2 + s) * P_DIM + p] = e;
    }
}

// ---- k3: per-mode scan over 4096 seg states, wave-shuffle version ----
__global__ __launch_bounds__(256) void k3(const float* __restrict__ E,
                                          const float* __restrict__ dA,
                                          float* __restrict__ Hin) {
    __shared__ float4 wagg[4];
    int m = blockIdx.x, t = threadIdx.x;
    int lane = t & 63, w = t >> 6;
    float2 aS = ((const float2*)dA)[m];
    #pragma unroll
    for (int i = 0; i < 5; ++i) aS = cmul(aS, aS);     // dA^32
    const float2* e = (const float2*)E;
    float2 ebuf[16];
    #pragma unroll
    for (int i = 0; i < 16; ++i) ebuf[i] = e[(size_t)(t * 16 + i) * P_DIM + m];
    float2 Bv = ebuf[0];
    #pragma unroll
    for (int i = 1; i < 16; ++i) Bv = cfma(aS, Bv, ebuf[i]);
    float2 Av = aS;
    #pragma unroll
    for (int i = 0; i < 4; ++i) Av = cmul(Av, Av);     // aS^16

    #pragma unroll
    for (int d = 1; d < 64; d <<= 1) {
        float uAx = __shfl_up(Av.x, (unsigned)d, 64);
        float uAy = __shfl_up(Av.y, (unsigned)d, 64);
        float uBx = __shfl_up(Bv.x, (unsigned)d, 64);
        float uBy = __shfl_up(Bv.y, (unsigned)d, 64);
        if (lane >= d) {
            float2 uA = make_float2(uAx, uAy), uB = make_float2(uBx, uBy);
            Bv = cfma(Av, uB, Bv);
            Av = cmul(uA, Av);
        }
    }
    if (lane == 63) wagg[w] = make_float4(Av.x, Av.y, Bv.x, Bv.y);
    __syncthreads();
    float2 Pb = make_float2(0.f, 0.f);
    for (int i = 0; i < w; ++i) {
        float4 u = wagg[i];
        float2 Wa = make_float2(u.x, u.y), Wb = make_float2(u.z, u.w);
        Pb = cfma(Wa, Pb, Wb);
    }
    float eAx = __shfl_up(Av.x, 1u, 64), eAy = __shfl_up(Av.y, 1u, 64);
    float eBx = __shfl_up(Bv.x, 1u, 64), eBy = __shfl_up(Bv.y, 1u, 64);
    float2 eA = make_float2(eAx, eAy), eB = make_float2(eBx, eBy);
    if (lane == 0) { eA = make_float2(1.f, 0.f); eB = make_float2(0.f, 0.f); }
    float2 pre = cfma(eA, Pb, eB);
    float2* hin = (float2*)Hin;
    #pragma unroll
    for (int i = 0; i < 16; ++i) {
        hin[(size_t)(t * 16 + i) * P_DIM + m] = pre;
        pre = cfma(aS, pre, ebuf[i]);
    }
}

// ---- k4: recompute pass; direct y store from acc2 (no SBF transpose) ----
__global__ __launch_bounds__(256) void k4(const float* __restrict__ x,
                                          const u16* __restrict__ W1F,
                                          const u16* __restrict__ W2F,
                                          const float* __restrict__ dA,
                                          const float* __restrict__ Hin,
                                          const float* __restrict__ Dv,
                                          float* __restrict__ y) {
    __shared__ __align__(16) char smem[32768];
    u16*   As_hi = (u16*)smem;               // [64][136] during stage
    u16*   SB    = (u16*)smem;               // [64][256] swizzled bf16, aliases As
    int t = threadIdx.x, lane = t & 63, wid = t >> 6;
    size_t l0 = (size_t)blockIdx.x * ROWS;
    int ar = lane & 15, aq = lane >> 4, ak = aq * 8;

    // W1F prefetch
    bf16x8 bhp[4][4];
    #pragma unroll
    for (int kt = 0; kt < 4; ++kt)
        #pragma unroll
        for (int nf = 0; nf < 4; ++nf)
            bhp[kt][nf] = *(const bf16x8*)(W1F + (size_t)(kt * 16 + wid * 4 + nf) * 1024 + lane * 8);

    // stage x -> bf16 LDS
    float4 xv[8];
    #pragma unroll
    for (int j = 0; j < 8; ++j) {
        int f = j * 256 + t; int row = f >> 5, c4 = f & 31;
        xv[j] = *(const float4*)(x + (l0 + row) * H_DIM + c4 * 4);
    }
    #pragma unroll
    for (int j = 0; j < 8; ++j) {
        int f = j * 256 + t; int row = f >> 5, c4 = f & 31;
        uint2 wv;
        wv.x = cvtpk(xv[j].x, xv[j].y);
        wv.y = cvtpk(xv[j].z, xv[j].w);
        *(uint2*)&As_hi[row * 136 + c4 * 4] = wv;
    }
    __syncthreads();

    // GEMM1: Bu = X @ W1
    {
        f32x4 acc[4][4];
        #pragma unroll
        for (int a = 0; a < 4; ++a)
            #pragma unroll
            for (int b = 0; b < 4; ++b) acc[a][b] = (f32x4)0.f;
        #pragma unroll
        for (int kt = 0; kt < 4; ++kt) {
            bf16x8 ah[4];
            #pragma unroll
            for (int mf = 0; mf < 4; ++mf)
                ah[mf] = *(const bf16x8*)&As_hi[(mf * 16 + ar) * 136 + kt * 32 + ak];
            #pragma unroll
            for (int nf = 0; nf < 4; ++nf)
                #pragma unroll
                for (int mf = 0; mf < 4; ++mf)
                    acc[mf][nf] = __builtin_amdgcn_mfma_f32_16x16x32_bf16(ah[mf], bhp[kt][nf], acc[mf][nf], 0, 0, 0);
        }
        __syncthreads();   // As reads done before SB overwrite
        int sr = aq * 4;
        #pragma unroll
        for (int mf = 0; mf < 4; ++mf)
            #pragma unroll
            for (int nf = 0; nf < 4; ++nf) {
                int col = wid * 64 + nf * 16 + ar;
                uint32 w01 = cvtpk(acc[mf][nf][0], acc[mf][nf][1]);
                uint32 w23 = cvtpk(acc[mf][nf][2], acc[mf][nf][3]);
                int r0 = mf * 16 + sr;
                SB[(r0 + 0) * 256 + (((col >> 3) ^ ((r0 + 0) & 7)) << 3) + (col & 7)] = (u16)w01;
                SB[(r0 + 1) * 256 + (((col >> 3) ^ ((r0 + 1) & 7)) << 3) + (col & 7)] = (u16)(w01 >> 16);
                SB[(r0 + 2) * 256 + (((col >> 3) ^ ((r0 + 2) & 7)) << 3) + (col & 7)] = (u16)w23;
                SB[(r0 + 3) * 256 + (((col >> 3) ^ ((r0 + 3) & 7)) << 3) + (col & 7)] = (u16)(w23 >> 16);
            }
    }
    __syncthreads();

    // W2F prefetch (GEMM1 acc dead; loads overlap the scan below)
    bf16x8 bh2[8][2];
    #pragma unroll
    for (int kk = 0; kk < 8; ++kk)
        #pragma unroll
        for (int nf = 0; nf < 2; ++nf)
            bh2[kk][nf] = *(const bf16x8*)(W2F + (size_t)(kk * 8 + wid * 2 + nf) * 1024 + lane * 8);

    // Hin-seeded scan: 2 segs x 128 modes
    {
        int s = t >> 7, p = t & 127;
        float2 a = ((const float2*)dA)[p];
        float2 h = ((const float2*)Hin)[((size_t)blockIdx.x * 2 + s) * P_DIM + p];
        uint32 buf[SEG];
        #pragma unroll
        for (int i = 0; i < SEG; ++i) {
            int row = s * 32 + i;
            buf[i] = *(const uint32*)&SB[row * 256 + (((p >> 2) ^ (row & 7)) << 3) + (p & 3) * 2];
        }
        #pragma unroll
        for (int i = 0; i < SEG; ++i) {
            h = cfma(a, h, unpk(buf[i]));
            buf[i] = cvtpk(h.x, h.y);
        }
        #pragma unroll
        for (int i = 0; i < SEG; ++i) {
            int row = s * 32 + i;
            *(uint32*)&SB[row * 256 + (((p >> 2) ^ (row & 7)) << 3) + (p & 3) * 2] = buf[i];
        }
    }
    __syncthreads();

    // GEMM2: y = h @ W2^T (64x32 wave tiles), direct store from fragments
    f32x4 acc2[4][2];
    #pragma unroll
    for (int a = 0; a < 4; ++a)
        #pragma unroll
        for (int b = 0; b < 2; ++b) acc2[a][b] = (f32x4)0.f;
    #pragma unroll
    for (int kk = 0; kk < 8; ++kk) {
        bf16x8 af[4];
        #pragma unroll
        for (int mf = 0; mf < 4; ++mf) {
            int row = mf * 16 + ar;
            int blk = kk * 4 + aq;
            af[mf] = *(const bf16x8*)&SB[row * 256 + ((blk ^ (row & 7)) << 3)];
        }
        #pragma unroll
        for (int nf = 0; nf < 2; ++nf)
            #pragma unroll
            for (int mf = 0; mf < 4; ++mf)
                acc2[mf][nf] = __builtin_amdgcn_mfma_f32_16x16x32_bf16(af[mf], bh2[kk][nf], acc2[mf][nf], 0, 0, 0);
    }

    // direct y store: per 16-lane group, 16 consecutive dwords = 64B chunks
    #pragma unroll
    for (int nf = 0; nf < 2; ++nf) {
        int col = wid * 32 + nf * 16 + ar;
        float d = Dv[col];
        #pragma unroll
        for (int mf = 0; mf < 4; ++mf)
            #pragma unroll
            for (int r = 0; r < 4; ++r) {
                int row = mf * 16 + aq * 4 + r;
                size_t idx = (l0 + row) * H_DIM + col;
                y[idx] = fmaf(x[idx], d, acc2[mf][nf][r]);
            }
    }
}

extern "C" void kernel_launch(void* const* d_in, const int* in_sizes, int n_in,
                              void* d_out, int out_size, void* d_ws, size_t ws_size,
                              hipStream_t stream) {
    const float* x     = (const float*)d_in[0];
    const float* Arl   = (const float*)d_in[1];
    const float* Ai    = (const float*)d_in[2];
    const float* Bre   = (const float*)d_in[3];
    const float* Bim   = (const float*)d_in[4];
    const float* Cre   = (const float*)d_in[5];
    const float* Cim   = (const float*)d_in[6];
    const float* Dv    = (const float*)d_in[7];
    const float* invdt = (const float*)d_in[8];
    float* y  = (float*)d_out;
    float* ws = (float*)d_ws;

    u16* w1f = (u16*)(ws + OFF_W1F);
    u16* w2f = (u16*)(ws + OFF_W2F);

    k0<<<32, 256, 0, stream>>>(Arl, Ai, invdt, Bre, Bim, Cre, Cim,
                               ws + OFF_DA, w1f, w2f);
    k1<<<NBLK, 256, 0, stream>>>(x, w1f, ws + OFF_DA, ws + OFF_E);
    k3<<<128, 256, 0, stream>>>(ws + OFF_E, ws + OFF_DA, ws + OFF_HIN);
    k4<<<NBLK, 256, 0, stream>>>(x, w1f, w2f, ws + OFF_DA,
                                 ws + OFF_HIN, Dv, y);
}

// Round 25
// 81.434 us; speedup vs baseline: 1.0429x; 1.0017x over previous
//
#include <hip/hip_runtime.h>

#define L_LEN 131072
#define H_DIM 128
#define P_DIM 128
#define SEG 32
#define NSEG (L_LEN / SEG)       // 4096
#define ROWS 64
#define NBLK (L_LEN / ROWS)      // 2048

typedef unsigned int uint32;
typedef unsigned short u16;
typedef short bf16x8 __attribute__((ext_vector_type(8)));
typedef float f32x4 __attribute__((ext_vector_type(4)));

// ---- workspace layout (float offsets) ----
constexpr size_t OFF_DA  = 0;                          // dA [128] cplx
constexpr size_t OFF_E   = OFF_DA + 256;               // E [NSEG][128] cplx
constexpr size_t OFF_HIN = OFF_E + (size_t)NSEG * 256; // Hin [NSEG][128] cplx
constexpr size_t OFF_W1F = OFF_HIN + (size_t)NSEG * 256;  // 65536 u16 = 32768 fl
constexpr size_t OFF_W2F = OFF_W1F + 32768;               // 65536 u16

__device__ __forceinline__ u16 f2bf(float v) {
    uint32 u = __builtin_bit_cast(uint32, v);
    uint32 r = u + 0x7FFFu + ((u >> 16) & 1u);
    return (u16)(r >> 16);
}
__device__ __forceinline__ float bf2f(u16 h) {
    uint32 u = ((uint32)h) << 16;
    return __builtin_bit_cast(float, u);
}
// HW packed f32->bf16 (RNE), 1 VALU op for 2 values
__device__ __forceinline__ uint32 cvtpk(float lo, float hi) {
    uint32 r;
    asm("v_cvt_pk_bf16_f32 %0, %1, %2" : "=v"(r) : "v"(lo), "v"(hi));
    return r;
}
__device__ __forceinline__ float2 cfma(float2 a, float2 h, float2 c) {
    float2 r;
    r.x = fmaf(a.x, h.x, fmaf(-a.y, h.y, c.x));
    r.y = fmaf(a.x, h.y, fmaf(a.y, h.x, c.y));
    return r;
}
__device__ __forceinline__ float2 cmul(float2 a, float2 b) {
    return make_float2(fmaf(a.x, b.x, -a.y * b.y), fmaf(a.x, b.y, a.y * b.x));
}
__device__ __forceinline__ float2 unpk(uint32 w) {
    return make_float2(bf2f((u16)(w & 0xffffu)), bf2f((u16)(w >> 16)));
}

// ---- k0: weight tables (sc inline) + block 0 does dA ----
__global__ void k0(const float* __restrict__ Arl, const float* __restrict__ Ai,
                   const float* __restrict__ invdt,
                   const float* __restrict__ Bre, const float* __restrict__ Bim,
                   const float* __restrict__ Cre, const float* __restrict__ Cim,
                   float* __restrict__ dA,
                   u16* __restrict__ W1F, u16* __restrict__ W2F) {
    int tid = blockIdx.x * 256 + threadIdx.x;    // 0..8191
    int lane = tid & 63;
    int fb = (tid >> 6) & 63;
    int ar = lane & 15, aq = lane >> 4;
    ushort4 hiA, hiB, loA, loB;
    u16* dst;
    if (tid < 4096) {
        int kt = fb >> 4, cf = fb & 15;
        int q = cf * 16 + ar;
        int p = q >> 1, c = q & 1;
        int h0 = kt * 32 + aq * 8;
        float idt = invdt[p];
        float dt = (idt > 20.f) ? idt : log1pf(expf(idt));
        float arl = Arl[p], aii = Ai[p];
        float zr = 0.5f * dt * arl, zi = 0.5f * dt * aii;
        float drr = 1.f - zr, dii = -zi;
        float inv = 1.f / (drr * drr + dii * dii);
        float blr = drr * inv, bli = -dii * inv;
        float2 s = make_float2(blr * dt, bli * dt);
        u16 hh[8], ll[8];
        #pragma unroll
        for (int j = 0; j < 8; ++j) {
            float br = Bre[p * H_DIM + h0 + j], bi = Bim[p * H_DIM + h0 + j];
            float re = fmaf(s.x, br, -s.y * bi);
            float im = fmaf(s.x, bi,  s.y * br);
            float v = c ? im : re;
            u16 h = f2bf(v); hh[j] = h; ll[j] = f2bf(v - bf2f(h));
        }
        hiA = make_ushort4(hh[0], hh[1], hh[2], hh[3]);
        hiB = make_ushort4(hh[4], hh[5], hh[6], hh[7]);
        loA = make_ushort4(ll[0], ll[1], ll[2], ll[3]);
        loB = make_ushort4(ll[4], ll[5], ll[6], ll[7]);
        dst = W1F + fb * 1024 + lane * 8;
    } else {
        int kk = fb >> 3, cf = fb & 7;
        int h = cf * 16 + ar;
        int q0 = kk * 32 + aq * 8;
        u16 hh[8], ll[8];
        #pragma unroll
        for (int j = 0; j < 8; ++j) {
            int q = q0 + j; int p = q >> 1;
            float v = (q & 1) ? (-2.f * Cim[h * P_DIM + p]) : (2.f * Cre[h * P_DIM + p]);
            u16 hv = f2bf(v); hh[j] = hv; ll[j] = f2bf(v - bf2f(hv));
        }
        hiA = make_ushort4(hh[0], hh[1], hh[2], hh[3]);
        hiB = make_ushort4(hh[4], hh[5], hh[6], hh[7]);
        loA = make_ushort4(ll[0], ll[1], ll[2], ll[3]);
        loB = make_ushort4(ll[4], ll[5], ll[6], ll[7]);
        dst = W2F + fb * 1024 + lane * 8;
    }
    *(ushort4*)(dst)       = hiA;
    *(ushort4*)(dst + 4)   = hiB;
    *(ushort4*)(dst + 512) = loA;
    *(ushort4*)(dst + 516) = loB;

    if (blockIdx.x == 0 && threadIdx.x < 128) {
        int p = threadIdx.x;
        float idt = invdt[p];
        float dt = (idt > 20.f) ? idt : log1pf(expf(idt));
        float arl = Arl[p], aii = Ai[p];
        float zr = 0.5f * dt * arl, zi = 0.5f * dt * aii;
        float drr = 1.f - zr, dii = -zi;
        float inv = 1.f / (drr * drr + dii * dii);
        float blr = drr * inv, bli = -dii * inv;
        float nr = 1.f + zr, ni = zi;
        dA[2 * p]     = fmaf(blr, nr, -bli * ni);
        dA[2 * p + 1] = fmaf(blr, ni,  bli * nr);
    }
}

// ---- k1: E-producer. stage x -> GEMM1 -> SB -> zero-seeded Horner -> E ----
__global__ __launch_bounds__(256) void k1(const float* __restrict__ x,
                                          const u16* __restrict__ W1F,
                                          const float* __restrict__ dA,
                                          float* __restrict__ E) {
    __shared__ __align__(16) char smem[32768];
    u16* As_hi = (u16*)smem;                 // [64][136]
    u16* SB    = (u16*)smem;                 // [64][256], aliases As
    int t = threadIdx.x, lane = t & 63, wid = t >> 6;
    size_t l0 = (size_t)blockIdx.x * ROWS;
    int ar = lane & 15, aq = lane >> 4, ak = aq * 8;

    bf16x8 bhp[4][4];
    #pragma unroll
    for (int kt = 0; kt < 4; ++kt)
        #pragma unroll
        for (int nf = 0; nf < 4; ++nf)
            bhp[kt][nf] = *(const bf16x8*)(W1F + (size_t)(kt * 16 + wid * 4 + nf) * 1024 + lane * 8);

    float4 xv[8];
    #pragma unroll
    for (int j = 0; j < 8; ++j) {
        int f = j * 256 + t; int row = f >> 5, c4 = f & 31;
        xv[j] = *(const float4*)(x + (l0 + row) * H_DIM + c4 * 4);
    }
    #pragma unroll
    for (int j = 0; j < 8; ++j) {
        int f = j * 256 + t; int row = f >> 5, c4 = f & 31;
        uint2 wv;
        wv.x = cvtpk(xv[j].x, xv[j].y);
        wv.y = cvtpk(xv[j].z, xv[j].w);
        *(uint2*)&As_hi[row * 136 + c4 * 4] = wv;
    }
    __syncthreads();

    f32x4 acc[4][4];
    #pragma unroll
    for (int a = 0; a < 4; ++a)
        #pragma unroll
        for (int b = 0; b < 4; ++b) acc[a][b] = (f32x4)0.f;
    #pragma unroll
    for (int kt = 0; kt < 4; ++kt) {
        bf16x8 ah[4];
        #pragma unroll
        for (int mf = 0; mf < 4; ++mf)
            ah[mf] = *(const bf16x8*)&As_hi[(mf * 16 + ar) * 136 + kt * 32 + ak];
        #pragma unroll
        for (int nf = 0; nf < 4; ++nf)
            #pragma unroll
            for (int mf = 0; mf < 4; ++mf)
                acc[mf][nf] = __builtin_amdgcn_mfma_f32_16x16x32_bf16(ah[mf], bhp[kt][nf], acc[mf][nf], 0, 0, 0);
    }
    __syncthreads();   // As reads done before SB overwrite

    int sr = aq * 4;
    #pragma unroll
    for (int mf = 0; mf < 4; ++mf)
        #pragma unroll
        for (int nf = 0; nf < 4; ++nf) {
            int col = wid * 64 + nf * 16 + ar;
            uint32 w01 = cvtpk(acc[mf][nf][0], acc[mf][nf][1]);
            uint32 w23 = cvtpk(acc[mf][nf][2], acc[mf][nf][3]);
            int r0 = mf * 16 + sr;
            SB[(r0 + 0) * 256 + (((col >> 3) ^ ((r0 + 0) & 7)) << 3) + (col & 7)] = (u16)w01;
            SB[(r0 + 1) * 256 + (((col >> 3) ^ ((r0 + 1) & 7)) << 3) + (col & 7)] = (u16)(w01 >> 16);
            SB[(r0 + 2) * 256 + (((col >> 3) ^ ((r0 + 2) & 7)) << 3) + (col & 7)] = (u16)w23;
            SB[(r0 + 3) * 256 + (((col >> 3) ^ ((r0 + 3) & 7)) << 3) + (col & 7)] = (u16)(w23 >> 16);
        }
    __syncthreads();

    // zero-seeded Horner over each seg -> E (no write-back, no HL)
    {
        int s = t >> 7, p = t & 127;
        float2 a = ((const float2*)dA)[p];
        uint32 buf[SEG];
        #pragma unroll
        for (int i = 0; i < SEG; ++i) {
            int row = s * 32 + i;
            buf[i] = *(const uint32*)&SB[row * 256 + (((p >> 2) ^ (row & 7)) << 3) + (p & 3) * 2];
        }
        float2 e = make_float2(0.f, 0.f);
        #pragma unroll
        for (int i = 0; i < SEG; ++i) e = cfma(a, e, unpk(buf[i]));
        ((float2*)E)[((size_t)blockIdx.x * 2 + s) * P_DIM + p] = e;
    }
}

// ---- k3: per-mode scan over 4096 seg states, wave-shuffle version ----
__global__ __launch_bounds__(256) void k3(const float* __restrict__ E,
                                          const float* __restrict__ dA,
                                          float* __restrict__ Hin) {
    __shared__ float4 wagg[4];
    int m = blockIdx.x, t = threadIdx.x;
    int lane = t & 63, w = t >> 6;
    float2 aS = ((const float2*)dA)[m];
    #pragma unroll
    for (int i = 0; i < 5; ++i) aS = cmul(aS, aS);     // dA^32
    const float2* e = (const float2*)E;
    float2 ebuf[16];
    #pragma unroll
    for (int i = 0; i < 16; ++i) ebuf[i] = e[(size_t)(t * 16 + i) * P_DIM + m];
    float2 Bv = ebuf[0];
    #pragma unroll
    for (int i = 1; i < 16; ++i) Bv = cfma(aS, Bv, ebuf[i]);
    float2 Av = aS;
    #pragma unroll
    for (int i = 0; i < 4; ++i) Av = cmul(Av, Av);     // aS^16

    #pragma unroll
    for (int d = 1; d < 64; d <<= 1) {
        float uAx = __shfl_up(Av.x, (unsigned)d, 64);
        float uAy = __shfl_up(Av.y, (unsigned)d, 64);
        float uBx = __shfl_up(Bv.x, (unsigned)d, 64);
        float uBy = __shfl_up(Bv.y, (unsigned)d, 64);
        if (lane >= d) {
            float2 uA = make_float2(uAx, uAy), uB = make_float2(uBx, uBy);
            Bv = cfma(Av, uB, Bv);
            Av = cmul(uA, Av);
        }
    }
    if (lane == 63) wagg[w] = make_float4(Av.x, Av.y, Bv.x, Bv.y);
    __syncthreads();
    float2 Pb = make_float2(0.f, 0.f);
    for (int i = 0; i < w; ++i) {
        float4 u = wagg[i];
        float2 Wa = make_float2(u.x, u.y), Wb = make_float2(u.z, u.w);
        Pb = cfma(Wa, Pb, Wb);
    }
    float eAx = __shfl_up(Av.x, 1u, 64), eAy = __shfl_up(Av.y, 1u, 64);
    float eBx = __shfl_up(Bv.x, 1u, 64), eBy = __shfl_up(Bv.y, 1u, 64);
    float2 eA = make_float2(eAx, eAy), eB = make_float2(eBx, eBy);
    if (lane == 0) { eA = make_float2(1.f, 0.f); eB = make_float2(0.f, 0.f); }
    float2 pre = cfma(eA, Pb, eB);
    float2* hin = (float2*)Hin;
    #pragma unroll
    for (int i = 0; i < 16; ++i) {
        hin[(size_t)(t * 16 + i) * P_DIM + m] = pre;
        pre = cfma(aS, pre, ebuf[i]);
    }
}

// ---- k4: recompute pass; direct y store from acc2 (no SBF transpose) ----
__global__ __launch_bounds__(256) void k4(const float* __restrict__ x,
                                          const u16* __restrict__ W1F,
                                          const u16* __restrict__ W2F,
                                          const float* __restrict__ dA,
                                          const float* __restrict__ Hin,
                                          const float* __restrict__ Dv,
                                          float* __restrict__ y) {
    __shared__ __align__(16) char smem[32768];
    u16*   As_hi = (u16*)smem;               // [64][136] during stage
    u16*   SB    = (u16*)smem;               // [64][256] swizzled bf16, aliases As
    int t = threadIdx.x, lane = t & 63, wid = t >> 6;
    size_t l0 = (size_t)blockIdx.x * ROWS;
    int ar = lane & 15, aq = lane >> 4, ak = aq * 8;

    // W1F prefetch
    bf16x8 bhp[4][4];
    #pragma unroll
    for (int kt = 0; kt < 4; ++kt)
        #pragma unroll
        for (int nf = 0; nf < 4; ++nf)
            bhp[kt][nf] = *(const bf16x8*)(W1F + (size_t)(kt * 16 + wid * 4 + nf) * 1024 + lane * 8);

    // stage x -> bf16 LDS
    float4 xv[8];
    #pragma unroll
    for (int j = 0; j < 8; ++j) {
        int f = j * 256 + t; int row = f >> 5, c4 = f & 31;
        xv[j] = *(const float4*)(x + (l0 + row) * H_DIM + c4 * 4);
    }
    #pragma unroll
    for (int j = 0; j < 8; ++j) {
        int f = j * 256 + t; int row = f >> 5, c4 = f & 31;
        uint2 wv;
        wv.x = cvtpk(xv[j].x, xv[j].y);
        wv.y = cvtpk(xv[j].z, xv[j].w);
        *(uint2*)&As_hi[row * 136 + c4 * 4] = wv;
    }
    __syncthreads();

    // GEMM1: Bu = X @ W1
    {
        f32x4 acc[4][4];
        #pragma unroll
        for (int a = 0; a < 4; ++a)
            #pragma unroll
            for (int b = 0; b < 4; ++b) acc[a][b] = (f32x4)0.f;
        #pragma unroll
        for (int kt = 0; kt < 4; ++kt) {
            bf16x8 ah[4];
            #pragma unroll
            for (int mf = 0; mf < 4; ++mf)
                ah[mf] = *(const bf16x8*)&As_hi[(mf * 16 + ar) * 136 + kt * 32 + ak];
            #pragma unroll
            for (int nf = 0; nf < 4; ++nf)
                #pragma unroll
                for (int mf = 0; mf < 4; ++mf)
                    acc[mf][nf] = __builtin_amdgcn_mfma_f32_16x16x32_bf16(ah[mf], bhp[kt][nf], acc[mf][nf], 0, 0, 0);
        }
        __syncthreads();   // As reads done before SB overwrite
        int sr = aq * 4;
        #pragma unroll
        for (int mf = 0; mf < 4; ++mf)
            #pragma unroll
            for (int nf = 0; nf < 4; ++nf) {
                int col = wid * 64 + nf * 16 + ar;
                uint32 w01 = cvtpk(acc[mf][nf][0], acc[mf][nf][1]);
                uint32 w23 = cvtpk(acc[mf][nf][2], acc[mf][nf][3]);
                int r0 = mf * 16 + sr;
                SB[(r0 + 0) * 256 + (((col >> 3) ^ ((r0 + 0) & 7)) << 3) + (col & 7)] = (u16)w01;
                SB[(r0 + 1) * 256 + (((col >> 3) ^ ((r0 + 1) & 7)) << 3) + (col & 7)] = (u16)(w01 >> 16);
                SB[(r0 + 2) * 256 + (((col >> 3) ^ ((r0 + 2) & 7)) << 3) + (col & 7)] = (u16)w23;
                SB[(r0 + 3) * 256 + (((col >> 3) ^ ((r0 + 3) & 7)) << 3) + (col & 7)] = (u16)(w23 >> 16);
            }
    }
    __syncthreads();

    // W2F prefetch (GEMM1 acc dead; loads overlap the scan below)
    bf16x8 bh2[8][2];
    #pragma unroll
    for (int kk = 0; kk < 8; ++kk)
        #pragma unroll
        for (int nf = 0; nf < 2; ++nf)
            bh2[kk][nf] = *(const bf16x8*)(W2F + (size_t)(kk * 8 + wid * 2 + nf) * 1024 + lane * 8);

    // Hin-seeded scan: 2 segs x 128 modes
    {
        int s = t >> 7, p = t & 127;
        float2 a = ((const float2*)dA)[p];
        float2 h = ((const float2*)Hin)[((size_t)blockIdx.x * 2 + s) * P_DIM + p];
        uint32 buf[SEG];
        #pragma unroll
        for (int i = 0; i < SEG; ++i) {
            int row = s * 32 + i;
            buf[i] = *(const uint32*)&SB[row * 256 + (((p >> 2) ^ (row & 7)) << 3) + (p & 3) * 2];
        }
        #pragma unroll
        for (int i = 0; i < SEG; ++i) {
            h = cfma(a, h, unpk(buf[i]));
            buf[i] = cvtpk(h.x, h.y);
        }
        #pragma unroll
        for (int i = 0; i < SEG; ++i) {
            int row = s * 32 + i;
            *(uint32*)&SB[row * 256 + (((p >> 2) ^ (row & 7)) << 3) + (p & 3) * 2] = buf[i];
        }
    }
    __syncthreads();

    // GEMM2: y = h @ W2^T (64x32 wave tiles), direct store from fragments
    f32x4 acc2[4][2];
    #pragma unroll
    for (int a = 0; a < 4; ++a)
        #pragma unroll
        for (int b = 0; b < 2; ++b) acc2[a][b] = (f32x4)0.f;
    #pragma unroll
    for (int kk = 0; kk < 8; ++kk) {
        bf16x8 af[4];
        #pragma unroll
        for (int mf = 0; mf < 4; ++mf) {
            int row = mf * 16 + ar;
            int blk = kk * 4 + aq;
            af[mf] = *(const bf16x8*)&SB[row * 256 + ((blk ^ (row & 7)) << 3)];
        }
        #pragma unroll
        for (int nf = 0; nf < 2; ++nf)
            #pragma unroll
            for (int mf = 0; mf < 4; ++mf)
                acc2[mf][nf] = __builtin_amdgcn_mfma_f32_16x16x32_bf16(af[mf], bh2[kk][nf], acc2[mf][nf], 0, 0, 0);
    }

    // direct y store: per 16-lane group, 16 consecutive dwords = 64B chunks
    #pragma unroll
    for (int nf = 0; nf < 2; ++nf) {
        int col = wid * 32 + nf * 16 + ar;
        float d = Dv[col];
        #pragma unroll
        for (int mf = 0; mf < 4; ++mf)
            #pragma unroll
            for (int r = 0; r < 4; ++r) {
                int row = mf * 16 + aq * 4 + r;
                size_t idx = (l0 + row) * H_DIM + col;
                y[idx] = fmaf(x[idx], d, acc2[mf][nf][r]);
            }
    }
}

extern "C" void kernel_launch(void* const* d_in, const int* in_sizes, int n_in,
                              void* d_out, int out_size, void* d_ws, size_t ws_size,
                              hipStream_t stream) {
    const float* x     = (const float*)d_in[0];
    const float* Arl   = (const float*)d_in[1];
    const float* Ai    = (const float*)d_in[2];
    const float* Bre   = (const float*)d_in[3];
    const float* Bim   = (const float*)d_in[4];
    const float* Cre   = (const float*)d_in[5];
    const float* Cim   = (const float*)d_in[6];
    const float* Dv    = (const float*)d_in[7];
    const float* invdt = (const float*)d_in[8];
    float* y  = (float*)d_out;
    float* ws = (float*)d_ws;

    u16* w1f = (u16*)(ws + OFF_W1F);
    u16* w2f = (u16*)(ws + OFF_W2F);

    k0<<<32, 256, 0, stream>>>(Arl, Ai, invdt, Bre, Bim, Cre, Cim,
                               ws + OFF_DA, w1f, w2f);
    k1<<<NBLK, 256, 0, stream>>>(x, w1f, ws + OFF_DA, ws + OFF_E);
    k3<<<128, 256, 0, stream>>>(ws + OFF_E, ws + OFF_DA, ws + OFF_HIN);
    k4<<<NBLK, 256, 0, stream>>>(x, w1f, w2f, ws + OFF_DA,
                                 ws + OFF_HIN, Dv, y);
}